// Round 7
// baseline (129.635 us; speedup 1.0000x reference)
//
#include <hip/hip_runtime.h>
#include <hip/hip_bf16.h>

// Windowed attention smoothing via MFMA — barrier-free, per-wave autonomous.
// v6 = v5 (42.4us) + P4 prob-broadcast via LDS instead of 176 v_readlane:
//   - quad0 writes p[0..10] to P_lds[16][12]; P4 reads 3 uniform-addr
//     ds_read_b128 per row (uniform = broadcast, conflict-free).
//   - Sc trimmed to 26 rows (rows 26..31 were dead) to fit P_lds at the
//     same 4-blocks/CU LDS footprint (40608 B).
//   - stage loads issued before M2 (more latency cover).
// No __syncthreads: LDS regions are wave-private; DS pipe is in-order
// within a wave.
//
// (2nd resubmission: rounds 5 and 6 both failed on container infra before
//  executing anything; kernel unchanged to keep attribution clean.)
//
// rows=200000, RANK=64, WINDOW=11. Block=256 (4 waves), 16 rows/wave/tile.

constexpr int RANK   = 64;
constexpr int WINDOW = 11;
constexpr int PAD    = 5;
constexpr int TILE   = 16;   // rows per wave
constexpr int BLOCK  = 256;  // 4 waves
constexpr int TR     = 64;   // rows per block-tile
constexpr int BROWS  = 28;   // staged band rows (rw-5 .. rw+22)
constexpr int BSTR   = 68;   // band row stride (floats): 272B, 16B-aligned
constexpr int SC_R   = 26;   // Sc rows kept (reads touch rows 0..25 only)
constexpr int SC_S   = 17;   // f32 elems per Sc row (breaks pow2)
constexpr int P_S    = 12;   // prob row stride (48B, 16B-aligned)
constexpr int GRIDB  = 1024; // 4 resident blocks/CU x 256 CU

constexpr int BAND_F = BROWS * BSTR;            // 1904 floats per wave
constexpr int SC_OFF = 4 * BAND_F;              // 7616
constexpr int P_OFF  = SC_OFF + 4 * SC_R * SC_S; // 7616+1768 = 9384
constexpr int SMEMF  = P_OFF + 4 * TILE * P_S;  // 10152 floats = 40608 B

typedef short short8  __attribute__((ext_vector_type(8)));
typedef float float4v __attribute__((ext_vector_type(4)));

__device__ __forceinline__ short8 cvt_bf8(float4 a, float4 b) {
    union { short8 s; __hip_bfloat162 h[4]; } u;
    u.h[0] = __float22bfloat162_rn(make_float2(a.x, a.y));
    u.h[1] = __float22bfloat162_rn(make_float2(a.z, a.w));
    u.h[2] = __float22bfloat162_rn(make_float2(b.x, b.y));
    u.h[3] = __float22bfloat162_rn(make_float2(b.z, b.w));
    return u.s;
}

__device__ __forceinline__ float fast_tanh(float x) {
    return 1.0f - 2.0f / (1.0f + __expf(2.0f * x));
}

__global__ __launch_bounds__(BLOCK)
__attribute__((amdgpu_waves_per_eu(4, 4)))
void attn_win_kernel(
    const float* __restrict__ A,   // (rows, 64)
    const float* __restrict__ W,   // (64, 64) row-major (out,in)
    const float* __restrict__ b,   // (64,)
    float* __restrict__ out,       // (rows, 64)
    int rows)
{
    // Flat LDS so deliberate band-row over-reads (rows 28..31, dead data)
    // stay in-bounds of the block allocation.
    __shared__ __align__(16) float smem[SMEMF];

    const int lane = threadIdx.x & 63;
    const int wv   = threadIdx.x >> 6;
    const int m16  = lane & 15;
    const int quad = lane >> 4;
    const int sr   = lane >> 4;        // staging: row within group-of-4
    const int sc4  = (lane & 15) * 4;  // staging: col base (float4)

    float* const bandW = smem + wv * BAND_F;                 // [28][68]
    float* const ScW   = smem + SC_OFF + wv * SC_R * SC_S;   // [26][17]
    float* const PW    = smem + P_OFF + wv * TILE * P_S;     // [16][12]

    // ---- Persistent W fragments (32 VGPRs) + transposed bias, loaded ONCE ----
    short8 wfrag[4][2];  // [ct][kf]: W[ct*16+m16][kf*32 + quad*8 + j]
    #pragma unroll
    for (int ct = 0; ct < 4; ct++) {
        #pragma unroll
        for (int kf = 0; kf < 2; kf++) {
            const float4* p =
                (const float4*)(W + (ct * 16 + m16) * RANK + kf * 32 + quad * 8);
            wfrag[ct][kf] = cvt_bf8(p[0], p[1]);
        }
    }
    float4 biasT[4];
    #pragma unroll
    for (int ct = 0; ct < 4; ct++)
        biasT[ct] = *(const float4*)(b + ct * 16 + quad * 4);

    // bpermute source-lane indices (byte units): word w of B-frag comes from
    // lane m16 + 16*(2*(quad&1) + (w>>1)).
    const int idxA = 4 * m16 + 128 * (quad & 1);
    const int idxB = idxA + 64;

    const int n_btiles = (rows + TR - 1) / TR;
    int bt = blockIdx.x;
    if (bt >= n_btiles) return;

    // ---- prologue: stage FIRST tile's 28-row fp32 band (guarded) ----
    {
        const int rw0 = bt * TR + wv * TILE;
        #pragma unroll
        for (int ro = 0; ro < 7; ro++) {
            const int g = rw0 - PAD + ro * 4 + sr;
            float4 x = make_float4(0.f, 0.f, 0.f, 0.f);
            if ((unsigned)g < (unsigned)rows)
                x = *(const float4*)(A + (size_t)g * RANK + sc4);
            *(float4*)&bandW[(ro * 4 + sr) * BSTR + sc4] = x;
        }
    }

    for (; bt < n_btiles; bt += gridDim.x) {
        const int rw = bt * TR + wv * TILE;   // this wave's rows rw..rw+15

        // ---- am1 frags from band (fp32 -> bf16): A rows rw+m16 ----
        short8 am1[2];
        #pragma unroll
        for (int kf = 0; kf < 2; kf++) {
            const float4* pp =
                (const float4*)&bandW[(PAD + m16) * BSTR + kf * 32 + quad * 8];
            am1[kf] = cvt_bf8(pp[0], pp[1]);
        }

        // ---- M1 (transposed): accT[ct] = W-block(ct) x A^T + b ----
        // C element: v1[m = m16][n = ct*16 + quad*4 + r]
        float4v accT[4];
        #pragma unroll
        for (int ct = 0; ct < 4; ct++)
            accT[ct] = (float4v){biasT[ct].x, biasT[ct].y,
                                 biasT[ct].z, biasT[ct].w};
        #pragma unroll
        for (int kf = 0; kf < 2; kf++)
            #pragma unroll
            for (int ct = 0; ct < 4; ct++)
                accT[ct] = __builtin_amdgcn_mfma_f32_16x16x32_bf16(
                    wfrag[ct][kf], am1[kf], accT[ct], 0, 0, 0);

        // ---- tanh + pack to bf16 pairs ----
        int pk[4][2];
        #pragma unroll
        for (int ct = 0; ct < 4; ct++)
            #pragma unroll
            for (int u = 0; u < 2; u++) {
                union { __hip_bfloat162 h; int i; } cv;
                cv.h = __float22bfloat162_rn(make_float2(
                    fast_tanh(accT[ct][2 * u]),
                    fast_tanh(accT[ct][2 * u + 1])));
                pk[ct][u] = cv.i;
            }

        // ---- M2 B-frag gather via ds_bpermute (no LDS storage) ----
        short8 bfr[2];
        #pragma unroll
        for (int kf = 0; kf < 2; kf++) {
            union { int w[4]; short8 s; } u;
            #pragma unroll
            for (int w = 0; w < 4; w++) {
                const int idx = (w >> 1) ? idxB : idxA;
                const int lo = __builtin_amdgcn_ds_bpermute(idx, pk[2 * kf][w & 1]);
                const int hi = __builtin_amdgcn_ds_bpermute(idx, pk[2 * kf + 1][w & 1]);
                u.w[w] = (quad >= 2) ? hi : lo;
            }
            bfr[kf] = u.s;
        }

        // ---- abnd frags: band rows it*16+m16 (rows 28..31 are dead reads) ----
        short8 abnd[2][2];
        #pragma unroll
        for (int it = 0; it < 2; it++)
            #pragma unroll
            for (int kf = 0; kf < 2; kf++) {
                const float4* pp = (const float4*)
                    &bandW[(it * 16 + m16) * BSTR + kf * 32 + quad * 8];
                abnd[it][kf] = cvt_bf8(pp[0], pp[1]);
            }

        // ---- issue NEXT tile's stage loads EARLY (cover under M2+softmax) ----
        float4 stg[7];
        {
            const int rwn = rw + (int)gridDim.x * TR;
            #pragma unroll
            for (int ro = 0; ro < 7; ro++) {
                const int g = rwn - PAD + ro * 4 + sr;
                stg[ro] = make_float4(0.f, 0.f, 0.f, 0.f);
                if ((unsigned)g < (unsigned)rows)
                    stg[ro] = *(const float4*)(A + (size_t)g * RANK + sc4);
            }
        }

        // ---- M2: S[i][q] = dot(band[i], v1[q]) ----
        float4v sacc[2];
        sacc[0] = (float4v){0.f, 0.f, 0.f, 0.f};
        sacc[1] = (float4v){0.f, 0.f, 0.f, 0.f};
        #pragma unroll
        for (int kf = 0; kf < 2; kf++)
            #pragma unroll
            for (int it = 0; it < 2; it++)
                sacc[it] = __builtin_amdgcn_mfma_f32_16x16x32_bf16(
                    abnd[it][kf], bfr[kf], sacc[it], 0, 0, 0);

        // scatter S (i = it*16+quad*4+rg, q = m16); keep rows < 26 only
        #pragma unroll
        for (int it = 0; it < 2; it++)
            #pragma unroll
            for (int rg = 0; rg < 4; rg++)
                if (it == 0 || quad * 4 + rg < 10)
                    ScW[(it * 16 + quad * 4 + rg) * SC_S + m16] = sacc[it][rg];

        // ---- softmax over band i in [q, q+10] of column q=m16 ----
        // (redundant across quads; row q=m16's probs end up in P_lds)
        float p[WINDOW];
        {
            float s[WINDOW];
            float mx = -1e30f;
            #pragma unroll
            for (int w = 0; w < WINDOW; w++) {
                s[w] = ScW[(m16 + w) * SC_S + m16];
                mx = fmaxf(mx, s[w]);
            }
            float den = 0.0f;
            #pragma unroll
            for (int w = 0; w < WINDOW; w++) {
                p[w] = __expf((s[w] - mx) * 0.125f);  // 1/sqrt(64) folded in
                den += p[w];
            }
            const float rden = __fdividef(1.0f, den);
            #pragma unroll
            for (int w = 0; w < WINDOW; w++) p[w] *= rden;
        }

        // ---- publish probs: quad0 lanes write row m16's p[0..10] ----
        if (quad == 0) {
            #pragma unroll
            for (int w = 0; w < WINDOW; w++)
                PW[m16 * P_S + w] = p[w];
        }

        // ---- aw: fp32 window, last reads of the current band ----
        float aw[26];
        #pragma unroll
        for (int s = 0; s < 26; s++) aw[s] = bandW[s * BSTR + lane];

        // ---- overwrite band with NEXT tile's rows (DS in-order per wave) ----
        #pragma unroll
        for (int ro = 0; ro < 7; ro++)
            *(float4*)&bandW[(ro * 4 + sr) * BSTR + sc4] = stg[ro];

        // ---- P4: out[rw+rr][lane] = sum_w P[rr][w] * aw[rr+w] ----
        // Probs via uniform-address b128 LDS reads (broadcast, no conflicts).
        #pragma unroll
        for (int rr = 0; rr < TILE; rr++) {
            const float4v pv0 = *(const float4v*)&PW[rr * P_S + 0];
            const float4v pv1 = *(const float4v*)&PW[rr * P_S + 4];
            const float4v pv2 = *(const float4v*)&PW[rr * P_S + 8];
            float o = 0.0f;
            o = fmaf(pv0[0], aw[rr + 0], o);
            o = fmaf(pv0[1], aw[rr + 1], o);
            o = fmaf(pv0[2], aw[rr + 2], o);
            o = fmaf(pv0[3], aw[rr + 3], o);
            o = fmaf(pv1[0], aw[rr + 4], o);
            o = fmaf(pv1[1], aw[rr + 5], o);
            o = fmaf(pv1[2], aw[rr + 6], o);
            o = fmaf(pv1[3], aw[rr + 7], o);
            o = fmaf(pv2[0], aw[rr + 8], o);
            o = fmaf(pv2[1], aw[rr + 9], o);
            o = fmaf(pv2[2], aw[rr + 10], o);
            if (rw + rr < rows)   // wave-uniform scalar guard
                out[(size_t)(rw + rr) * RANK + lane] = o;
        }
    }
}

extern "C" void kernel_launch(void* const* d_in, const int* in_sizes, int n_in,
                              void* d_out, int out_size, void* d_ws, size_t ws_size,
                              hipStream_t stream) {
    const float* A = (const float*)d_in[0];
    const float* W = (const float*)d_in[1];
    const float* b = (const float*)d_in[2];
    float* out = (float*)d_out;

    const int rows     = in_sizes[0] / RANK;
    const int n_btiles = (rows + TR - 1) / TR;
    const int blocks   = n_btiles < GRIDB ? n_btiles : GRIDB;  // persistent

    hipLaunchKernelGGL(attn_win_kernel, dim3(blocks), dim3(BLOCK), 0, stream,
                       A, W, b, out, rows);
}